// Round 4
// baseline (323.177 us; speedup 1.0000x reference)
//
#include <hip/hip_runtime.h>
#include <hip/hip_bf16.h>
#include <cstring>

// Problem constants (match reference)
#define NNODE_DIN 128
#define NNODE_DOUT 128
#define DEG 48
#define TOPK 32

typedef __bf16 bf16x8 __attribute__((ext_vector_type(8)));
typedef float floatx4 __attribute__((ext_vector_type(4)));

__device__ inline unsigned short f2bf(float f) {
    __bf16 h = (__bf16)f;
    return __builtin_bit_cast(unsigned short, h);
}
__device__ inline float bf2f(unsigned short u) {
    unsigned v = ((unsigned)u) << 16;
    return __builtin_bit_cast(float, v);
}

// ---------------------------------------------------------------------------
// Kernel 1: x = feat @ weight (fp32 accumulate). Store split-bf16: hi = bf16(x),
// lo = bf16(x - hi). Together ~2^-18 relative precision.
// Block = 256 threads; thread (c,rowgrp) computes 4 rows x 16 cols where the
// cols are {c*4 + cc*32 + e : cc in 0..3, e in 0..3}. With this ownership the
// wave-wide float4 LDS read at dword (row*128 + c*4 + cc*32) hits 8 DISTINCT
// bank quads (c*4 mod 32, 8-lane broadcast each) -> conflict-free.
// (Previous layout c*16+cc*4 was a 4-way conflict on every read -> ~118 us.)
// All acc[] indices compile-time (runtime indexing spills acc to scratch).
// ---------------------------------------------------------------------------
__global__ __launch_bounds__(256) void k1_gemm(
    const float* __restrict__ feat, const float* __restrict__ weight,
    unsigned short* __restrict__ xh, unsigned short* __restrict__ xl, int n) {
    __shared__ float s_wt[128 * 128];

    int t = threadIdx.x;
    const float4* wg4 = (const float4*)weight;
    float4* sw4 = (float4*)s_wt;
#pragma unroll
    for (int ii = 0; ii < 16; ++ii) sw4[ii * 256 + t] = wg4[ii * 256 + t];
    __syncthreads();

    int c = t & 7;        // colgrp
    int rowgrp = t >> 3;  // 32 rowgrps x 4 rows
    int r0 = blockIdx.x * 128 + rowgrp * 4;

    float acc[4][16];  // acc[j][cc*4+e] = out[r0+j][c*4 + cc*32 + e]
#pragma unroll
    for (int j = 0; j < 4; ++j)
#pragma unroll
        for (int cidx = 0; cidx < 16; ++cidx) acc[j][cidx] = 0.0f;

    for (int d0 = 0; d0 < 128; d0 += 4) {
        float4 f[4];
#pragma unroll
        for (int j = 0; j < 4; ++j) {
            int r = r0 + j;
            if (r < n) {
                f[j] = *(const float4*)(feat + (size_t)r * 128 + d0);
            } else {
                f[j] = make_float4(0.f, 0.f, 0.f, 0.f);
            }
        }
#pragma unroll
        for (int i = 0; i < 4; ++i) {
            float4 wv[4];
#pragma unroll
            for (int cc = 0; cc < 4; ++cc) {
                wv[cc] = *(const float4*)&s_wt[(d0 + i) * 128 + c * 4 + cc * 32];
            }
#pragma unroll
            for (int j = 0; j < 4; ++j) {
                float fv = (&f[j].x)[i];
#pragma unroll
                for (int cc = 0; cc < 4; ++cc) {
                    acc[j][cc * 4 + 0] = fmaf(fv, wv[cc].x, acc[j][cc * 4 + 0]);
                    acc[j][cc * 4 + 1] = fmaf(fv, wv[cc].y, acc[j][cc * 4 + 1]);
                    acc[j][cc * 4 + 2] = fmaf(fv, wv[cc].z, acc[j][cc * 4 + 2]);
                    acc[j][cc * 4 + 3] = fmaf(fv, wv[cc].w, acc[j][cc * 4 + 3]);
                }
            }
        }
    }

#pragma unroll
    for (int j = 0; j < 4; ++j) {
        int r = r0 + j;
        if (r < n) {
#pragma unroll
            for (int cc = 0; cc < 4; ++cc) {
                unsigned short h[4], lo[4];
#pragma unroll
                for (int e = 0; e < 4; ++e) {
                    float a = acc[j][cc * 4 + e];
                    h[e] = f2bf(a);
                    lo[e] = f2bf(a - bf2f(h[e]));
                }
                uint2 ph = make_uint2((unsigned)h[0] | ((unsigned)h[1] << 16),
                                      (unsigned)h[2] | ((unsigned)h[3] << 16));
                uint2 pl = make_uint2((unsigned)lo[0] | ((unsigned)lo[1] << 16),
                                      (unsigned)lo[2] | ((unsigned)lo[3] << 16));
                size_t off = (size_t)r * 128 + c * 4 + cc * 32;
                *(uint2*)(xh + off) = ph;
                *(uint2*)(xl + off) = pl;
            }
        }
    }
}

// ---------------------------------------------------------------------------
// Kernel 2: one wave (64 threads) per node. NO LDS staging of x: MFMA
// fragments are loaded directly from global (lane (m,q) reads row id[m],
// bytes kt*64 + q*16 — each 16B chunk of the 32 selected rows is fetched
// exactly once), and the final aggregation re-reads rows coalesced from
// global (L1/L2-warm). LDS is ~700 B -> occupancy VGPR-bound (launch_bounds
// (64,4) caps 128 VGPRs -> 16+ waves/CU vs 8 before).
// ---------------------------------------------------------------------------
__global__ __launch_bounds__(64, 4) void k2_conv(
    const float* __restrict__ ew, const int* __restrict__ nbr,
    const float* __restrict__ bias, const unsigned short* __restrict__ xh,
    const unsigned short* __restrict__ xl, float* __restrict__ outp, int n) {
    __shared__ float s_w[52];
    __shared__ int s_nb[52];
    __shared__ float s_tw[32];
    __shared__ int s_id[32];
    __shared__ float s_diag[32];
    __shared__ float s_dist[32];
    __shared__ float s_omega[32];

    int i = blockIdx.x;
    int l = threadIdx.x;

    // A: candidates = 48 neighbors + self loop (weight 1.0)
    if (l < DEG) {
        s_w[l] = ew[(size_t)i * DEG + l];
        s_nb[l] = nbr[(size_t)i * DEG + l];
    }
    if (l == DEG) {
        s_w[DEG] = 1.0f;
        s_nb[DEG] = i;
    }
    __syncthreads();

    // B: rank-based top-k (exact jax.lax.top_k tie semantics); rank == slot
    if (l < DEG + 1) {
        float wj = s_w[l];
        int rank = 0;
#pragma unroll
        for (int t2 = 0; t2 < DEG + 1; ++t2) {
            float wt = s_w[t2];
            rank += (wt > wj) || ((wt == wj) && (t2 < l)) ? 1 : 0;
        }
        if (rank < TOPK) {
            s_tw[rank] = wj;
            s_id[rank] = s_nb[l];
        }
    }
    __syncthreads();

    // C+D: Gram = X*X^T with X ~= H + L: G = HH^T + HL^T + LH^T
    // Fragments loaded straight from global in MFMA A-layout.
    int m = l & 15;
    int q = l >> 4;
    int row0 = s_id[m];
    int row1 = s_id[16 + m];
    const __bf16* gh0 = (const __bf16*)(xh + (size_t)row0 * 128) + q * 8;
    const __bf16* gh1 = (const __bf16*)(xh + (size_t)row1 * 128) + q * 8;
    const __bf16* gl0 = (const __bf16*)(xl + (size_t)row0 * 128) + q * 8;
    const __bf16* gl1 = (const __bf16*)(xl + (size_t)row1 * 128) + q * 8;

    floatx4 acc[2][2];
#pragma unroll
    for (int a = 0; a < 2; ++a)
#pragma unroll
        for (int b = 0; b < 2; ++b) acc[a][b] = (floatx4){0.f, 0.f, 0.f, 0.f};

#pragma unroll
    for (int kt = 0; kt < 4; ++kt) {
        bf16x8 h0 = *(const bf16x8*)(gh0 + kt * 32);
        bf16x8 h1 = *(const bf16x8*)(gh1 + kt * 32);
        bf16x8 l0 = *(const bf16x8*)(gl0 + kt * 32);
        bf16x8 l1 = *(const bf16x8*)(gl1 + kt * 32);
        acc[0][0] = __builtin_amdgcn_mfma_f32_16x16x32_bf16(h0, h0, acc[0][0], 0, 0, 0);
        acc[0][0] = __builtin_amdgcn_mfma_f32_16x16x32_bf16(h0, l0, acc[0][0], 0, 0, 0);
        acc[0][0] = __builtin_amdgcn_mfma_f32_16x16x32_bf16(l0, h0, acc[0][0], 0, 0, 0);
        acc[0][1] = __builtin_amdgcn_mfma_f32_16x16x32_bf16(h0, h1, acc[0][1], 0, 0, 0);
        acc[0][1] = __builtin_amdgcn_mfma_f32_16x16x32_bf16(h0, l1, acc[0][1], 0, 0, 0);
        acc[0][1] = __builtin_amdgcn_mfma_f32_16x16x32_bf16(l0, h1, acc[0][1], 0, 0, 0);
        acc[1][0] = __builtin_amdgcn_mfma_f32_16x16x32_bf16(h1, h0, acc[1][0], 0, 0, 0);
        acc[1][0] = __builtin_amdgcn_mfma_f32_16x16x32_bf16(h1, l0, acc[1][0], 0, 0, 0);
        acc[1][0] = __builtin_amdgcn_mfma_f32_16x16x32_bf16(l1, h0, acc[1][0], 0, 0, 0);
        acc[1][1] = __builtin_amdgcn_mfma_f32_16x16x32_bf16(h1, h1, acc[1][1], 0, 0, 0);
        acc[1][1] = __builtin_amdgcn_mfma_f32_16x16x32_bf16(h1, l1, acc[1][1], 0, 0, 0);
        acc[1][1] = __builtin_amdgcn_mfma_f32_16x16x32_bf16(l1, h1, acc[1][1], 0, 0, 0);
    }

    // D2: extract diagonal (sq) from Gram so that d2_aa == 0 exactly
    if (q == (m >> 2)) {
        int rd = m & 3;
        s_diag[m] = acc[0][0][rd];
        s_diag[16 + m] = acc[1][1][rd];
    }
    __syncthreads();

    // E: dist[a] = sum_b tw[b] * sqrt(d2 masked by d2>0)
#pragma unroll
    for (int ma = 0; ma < 2; ++ma) {
#pragma unroll
        for (int r = 0; r < 4; ++r) {
            int a = ma * 16 + q * 4 + r;
            float da = s_diag[a];
            float g0 = acc[ma][0][r];
            float g1 = acc[ma][1][r];
            int b0 = m;
            int b1 = 16 + m;
            float d20 = da + s_diag[b0] - 2.0f * g0;
            float d21 = da + s_diag[b1] - 2.0f * g1;
            float t0 = (d20 > 0.0f) ? sqrtf(d20) : 0.0f;
            float t1 = (d21 > 0.0f) ? sqrtf(d21) : 0.0f;
            float v = s_tw[b0] * t0 + s_tw[b1] * t1;
            v += __shfl_xor(v, 1);
            v += __shfl_xor(v, 2);
            v += __shfl_xor(v, 4);
            v += __shfl_xor(v, 8);
            if (m == 0) s_dist[a] = v;
        }
    }
    __syncthreads();

    // F: omega = exp(-dist - max(-dist)) * tw, normalized
    {
        int k32 = l & 31;
        float s = s_dist[k32];
        float mn = s;
        mn = fminf(mn, __shfl_xor(mn, 1));
        mn = fminf(mn, __shfl_xor(mn, 2));
        mn = fminf(mn, __shfl_xor(mn, 4));
        mn = fminf(mn, __shfl_xor(mn, 8));
        mn = fminf(mn, __shfl_xor(mn, 16));
        float e = expf(mn - s) * s_tw[k32];
        float sum = e;
        sum += __shfl_xor(sum, 1);
        sum += __shfl_xor(sum, 2);
        sum += __shfl_xor(sum, 4);
        sum += __shfl_xor(sum, 8);
        sum += __shfl_xor(sum, 16);
        float om = e / sum;
        if (l < 32) s_omega[l] = om;
    }
    __syncthreads();

    // G: out[i][d] = sum_k omega[k] * (hi+lo)[sel_k][d] + bias[d]; 2 cols/lane
    // Rows re-read coalesced from global (256 B/instr, L1/L2-warm).
    {
        int d0 = 2 * l;
        const float2* b2 = (const float2*)bias;
        float2 bb = b2[l];
        float o0 = bb.x;
        float o1 = bb.y;
#pragma unroll
        for (int k = 0; k < TOPK; ++k) {
            float wk = s_omega[k];
            size_t base = (size_t)s_id[k] * 128 + d0;
            unsigned ph = *(const unsigned*)(xh + base);
            unsigned pl = *(const unsigned*)(xl + base);
            float x0 = bf2f((unsigned short)(ph & 0xffffu)) +
                       bf2f((unsigned short)(pl & 0xffffu));
            float x1 = bf2f((unsigned short)(ph >> 16)) +
                       bf2f((unsigned short)(pl >> 16));
            o0 = fmaf(wk, x0, o0);
            o1 = fmaf(wk, x1, o1);
        }
        float2 o = make_float2(o0, o1);
        *(float2*)(outp + (size_t)i * 128 + d0) = o;
    }
}

extern "C" void kernel_launch(void* const* d_in, const int* in_sizes, int n_in,
                              void* d_out, int out_size, void* d_ws, size_t ws_size,
                              hipStream_t stream) {
    const float* feat = (const float*)d_in[0];
    const float* ew = (const float*)d_in[1];
    const float* weight = (const float*)d_in[2];
    const float* bias = (const float*)d_in[3];
    const int* nbr = (const int*)d_in[4];
    float* outp = (float*)d_out;
    int n = in_sizes[0] / NNODE_DIN;  // 50000

    unsigned short* xh = (unsigned short*)d_ws;            // n x 128 bf16
    unsigned short* xl = xh + (size_t)n * NNODE_DOUT;      // n x 128 bf16

    int grid1 = (n + 127) / 128;
    hipLaunchKernelGGL(k1_gemm, dim3(grid1), dim3(256), 0, stream, feat, weight, xh, xl, n);
    hipLaunchKernelGGL(k2_conv, dim3(n), dim3(64), 0, stream, ew, nbr, bias, xh, xl, outp, n);
}

// Round 5
// 239.088 us; speedup vs baseline: 1.3517x; 1.3517x over previous
//
#include <hip/hip_runtime.h>
#include <hip/hip_bf16.h>

// Problem constants (match reference)
#define NNODE_DIN 128
#define NNODE_DOUT 128
#define DEG 48
#define TOPK 32

typedef __bf16 bf16x8 __attribute__((ext_vector_type(8)));
typedef unsigned short ushortx8 __attribute__((ext_vector_type(8)));
typedef float floatx4 __attribute__((ext_vector_type(4)));

__device__ inline unsigned short f2bf(float f) {
    __bf16 h = (__bf16)f;
    return __builtin_bit_cast(unsigned short, h);
}
__device__ inline float bf2f(unsigned short u) {
    unsigned v = ((unsigned)u) << 16;
    return __builtin_bit_cast(float, v);
}

// ---------------------------------------------------------------------------
// Kernel 0: pre-swizzle W^T into split-bf16 MFMA B-fragments, in exactly the
// order k1's waves load them: frag (nt,kt,lane) holds W[k][n] for
// n = nt*16 + (lane&15), k = kt*32 + (lane>>4)*8 + e.  2048 frags x 16 B per
// array (hi, lo) = 64 KB total; k1 then loads b-frags with single fully
// coalesced dwordx4 (L2-resident after first touch).
// ---------------------------------------------------------------------------
__global__ __launch_bounds__(256) void k0_wprep(
    const float* __restrict__ w, unsigned short* __restrict__ wth,
    unsigned short* __restrict__ wtl) {
    int tid = blockIdx.x * 256 + threadIdx.x;  // 0..2047
    int lane = tid & 63;
    int kt = (tid >> 6) & 3;
    int nt = tid >> 8;
    int m = lane & 15, q = lane >> 4;
    int nn = nt * 16 + m;
    int k0 = kt * 32 + q * 8;
    ushortx8 uh, ul;
#pragma unroll
    for (int e = 0; e < 8; ++e) {
        float v = w[(size_t)(k0 + e) * 128 + nn];
        unsigned short h = f2bf(v);
        uh[e] = h;
        ul[e] = f2bf(v - bf2f(h));
    }
    *(ushortx8*)(wth + tid * 8) = uh;
    *(ushortx8*)(wtl + tid * 8) = ul;
}

// ---------------------------------------------------------------------------
// Kernel 1: x = feat @ W via split-bf16 MFMA (replaces VALU GEMM that was
// stuck at ~128 us, ~9x over its VALU floor — suspected residual spills).
// One wave per 16 rows: A-frags = feat rows converted to hi/lo bf16 on the
// fly; B-frags = pre-swizzled W^T from k0 (coalesced loads). 96 MFMAs/wave.
// Epilogue: transpose through LDS (stride 132: 2-way banks = free), split
// into hi/lo bf16, coalesced dwordx4 stores. Memory floor ~13 us.
// ---------------------------------------------------------------------------
__global__ __launch_bounds__(64) void k1_mfma(
    const float* __restrict__ feat, const unsigned short* __restrict__ wth,
    const unsigned short* __restrict__ wtl, unsigned short* __restrict__ xh,
    unsigned short* __restrict__ xl, int n) {
    __shared__ float s_x[16 * 132];
    int l = threadIdx.x;
    int m = l & 15, q = l >> 4;
    int r0 = blockIdx.x * 16;

    // A-fragments: feat rows r0+m, split into hi/lo bf16
    bf16x8 ah[4], al[4];
#pragma unroll
    for (int kt = 0; kt < 4; ++kt) {
        float vv[8];
        if (r0 + m < n) {
            const float* src = feat + (size_t)(r0 + m) * 128 + kt * 32 + q * 8;
            float4 v0 = *(const float4*)src;
            float4 v1 = *(const float4*)(src + 4);
            vv[0] = v0.x; vv[1] = v0.y; vv[2] = v0.z; vv[3] = v0.w;
            vv[4] = v1.x; vv[5] = v1.y; vv[6] = v1.z; vv[7] = v1.w;
        } else {
#pragma unroll
            for (int e = 0; e < 8; ++e) vv[e] = 0.0f;
        }
        ushortx8 uh, ul;
#pragma unroll
        for (int e = 0; e < 8; ++e) {
            unsigned short h = f2bf(vv[e]);
            uh[e] = h;
            ul[e] = f2bf(vv[e] - bf2f(h));
        }
        ah[kt] = __builtin_bit_cast(bf16x8, uh);
        al[kt] = __builtin_bit_cast(bf16x8, ul);
    }

    floatx4 acc[8];
#pragma unroll
    for (int nt = 0; nt < 8; ++nt) acc[nt] = (floatx4){0.f, 0.f, 0.f, 0.f};

#pragma unroll
    for (int kt = 0; kt < 4; ++kt) {
#pragma unroll
        for (int nt = 0; nt < 8; ++nt) {
            int fo = ((nt * 4 + kt) * 64 + l) * 8;
            bf16x8 bh = *(const bf16x8*)(wth + fo);
            bf16x8 bl = *(const bf16x8*)(wtl + fo);
            acc[nt] = __builtin_amdgcn_mfma_f32_16x16x32_bf16(ah[kt], bh, acc[nt], 0, 0, 0);
            acc[nt] = __builtin_amdgcn_mfma_f32_16x16x32_bf16(ah[kt], bl, acc[nt], 0, 0, 0);
            acc[nt] = __builtin_amdgcn_mfma_f32_16x16x32_bf16(al[kt], bh, acc[nt], 0, 0, 0);
        }
    }

    // D layout: acc[nt][r] = x[r0 + q*4 + r][nt*16 + m] -> transpose via LDS
#pragma unroll
    for (int nt = 0; nt < 8; ++nt)
#pragma unroll
        for (int r = 0; r < 4; ++r)
            s_x[(q * 4 + r) * 132 + nt * 16 + m] = acc[nt][r];
    __syncthreads();

#pragma unroll
    for (int rr = 0; rr < 2; ++rr) {
        int row = rr * 8 + (l >> 3);
        int c0 = (l & 7) * 16;
        if (r0 + row < n) {
            float vv[16];
#pragma unroll
            for (int j = 0; j < 4; ++j) {
                float4 v = *(const float4*)&s_x[row * 132 + c0 + j * 4];
                vv[j * 4 + 0] = v.x; vv[j * 4 + 1] = v.y;
                vv[j * 4 + 2] = v.z; vv[j * 4 + 3] = v.w;
            }
            unsigned uh[8], ul[8];
#pragma unroll
            for (int p = 0; p < 8; ++p) {
                unsigned short h0 = f2bf(vv[2 * p]);
                unsigned short h1 = f2bf(vv[2 * p + 1]);
                unsigned short l0 = f2bf(vv[2 * p] - bf2f(h0));
                unsigned short l1 = f2bf(vv[2 * p + 1] - bf2f(h1));
                uh[p] = (unsigned)h0 | ((unsigned)h1 << 16);
                ul[p] = (unsigned)l0 | ((unsigned)l1 << 16);
            }
            size_t off = (size_t)(r0 + row) * 128 + c0;
            *(uint4*)(xh + off) = make_uint4(uh[0], uh[1], uh[2], uh[3]);
            *(uint4*)(xh + off + 8) = make_uint4(uh[4], uh[5], uh[6], uh[7]);
            *(uint4*)(xl + off) = make_uint4(ul[0], ul[1], ul[2], ul[3]);
            *(uint4*)(xl + off + 8) = make_uint4(ul[4], ul[5], ul[6], ul[7]);
        }
    }
}

// ---------------------------------------------------------------------------
// Kernel 2: one wave per node. Fragments gathered ONCE from global into
// registers (16 dwordx4), used for both the Gram MFMAs AND the final
// aggregation (partial = omega_m * row_m per lane, reduced over the 16
// m-lanes through a pad-2 LDS buffer). This halves logical gather traffic
// vs round 4 (no global re-read in the epilogue).
// ---------------------------------------------------------------------------
__global__ __launch_bounds__(64, 4) void k2_conv(
    const float* __restrict__ ew, const int* __restrict__ nbr,
    const float* __restrict__ bias, const unsigned short* __restrict__ xh,
    const unsigned short* __restrict__ xl, float* __restrict__ outp, int n) {
    __shared__ float s_w[52];
    __shared__ int s_nb[52];
    __shared__ float s_tw[32];
    __shared__ int s_id[32];
    __shared__ float s_diag[32];
    __shared__ float s_dist[32];
    __shared__ float s_omega[32];
    __shared__ float s_red[16 * 130];  // stride 130: 2-way banks (free)

    int i = blockIdx.x;
    int l = threadIdx.x;

    // A: candidates = 48 neighbors + self loop (weight 1.0)
    if (l < DEG) {
        s_w[l] = ew[(size_t)i * DEG + l];
        s_nb[l] = nbr[(size_t)i * DEG + l];
    }
    if (l == DEG) {
        s_w[DEG] = 1.0f;
        s_nb[DEG] = i;
    }
    __syncthreads();

    // B: rank-based top-k (exact jax.lax.top_k tie semantics); rank == slot
    if (l < DEG + 1) {
        float wj = s_w[l];
        int rank = 0;
#pragma unroll
        for (int t2 = 0; t2 < DEG + 1; ++t2) {
            float wt = s_w[t2];
            rank += (wt > wj) || ((wt == wj) && (t2 < l)) ? 1 : 0;
        }
        if (rank < TOPK) {
            s_tw[rank] = wj;
            s_id[rank] = s_nb[l];
        }
    }
    __syncthreads();

    // C: gather all 16 fragments into registers (kept live through epilogue)
    int m = l & 15;
    int q = l >> 4;
    int row0 = s_id[m];
    int row1 = s_id[16 + m];
    const __bf16* gh0 = (const __bf16*)(xh + (size_t)row0 * 128) + q * 8;
    const __bf16* gh1 = (const __bf16*)(xh + (size_t)row1 * 128) + q * 8;
    const __bf16* gl0 = (const __bf16*)(xl + (size_t)row0 * 128) + q * 8;
    const __bf16* gl1 = (const __bf16*)(xl + (size_t)row1 * 128) + q * 8;

    bf16x8 H0[4], H1[4], L0[4], L1[4];
#pragma unroll
    for (int kt = 0; kt < 4; ++kt) {
        H0[kt] = *(const bf16x8*)(gh0 + kt * 32);
        H1[kt] = *(const bf16x8*)(gh1 + kt * 32);
        L0[kt] = *(const bf16x8*)(gl0 + kt * 32);
        L1[kt] = *(const bf16x8*)(gl1 + kt * 32);
    }

    // D: Gram = X*X^T with X ~= H + L: G = HH^T + HL^T + LH^T
    floatx4 acc[2][2];
#pragma unroll
    for (int a = 0; a < 2; ++a)
#pragma unroll
        for (int b = 0; b < 2; ++b) acc[a][b] = (floatx4){0.f, 0.f, 0.f, 0.f};

#pragma unroll
    for (int kt = 0; kt < 4; ++kt) {
        bf16x8 h0 = H0[kt], h1 = H1[kt], l0 = L0[kt], l1 = L1[kt];
        acc[0][0] = __builtin_amdgcn_mfma_f32_16x16x32_bf16(h0, h0, acc[0][0], 0, 0, 0);
        acc[0][0] = __builtin_amdgcn_mfma_f32_16x16x32_bf16(h0, l0, acc[0][0], 0, 0, 0);
        acc[0][0] = __builtin_amdgcn_mfma_f32_16x16x32_bf16(l0, h0, acc[0][0], 0, 0, 0);
        acc[0][1] = __builtin_amdgcn_mfma_f32_16x16x32_bf16(h0, h1, acc[0][1], 0, 0, 0);
        acc[0][1] = __builtin_amdgcn_mfma_f32_16x16x32_bf16(h0, l1, acc[0][1], 0, 0, 0);
        acc[0][1] = __builtin_amdgcn_mfma_f32_16x16x32_bf16(l0, h1, acc[0][1], 0, 0, 0);
        acc[1][0] = __builtin_amdgcn_mfma_f32_16x16x32_bf16(h1, h0, acc[1][0], 0, 0, 0);
        acc[1][0] = __builtin_amdgcn_mfma_f32_16x16x32_bf16(h1, l0, acc[1][0], 0, 0, 0);
        acc[1][0] = __builtin_amdgcn_mfma_f32_16x16x32_bf16(l1, h0, acc[1][0], 0, 0, 0);
        acc[1][1] = __builtin_amdgcn_mfma_f32_16x16x32_bf16(h1, h1, acc[1][1], 0, 0, 0);
        acc[1][1] = __builtin_amdgcn_mfma_f32_16x16x32_bf16(h1, l1, acc[1][1], 0, 0, 0);
        acc[1][1] = __builtin_amdgcn_mfma_f32_16x16x32_bf16(l1, h1, acc[1][1], 0, 0, 0);
    }

    // D2: extract diagonal (sq) from Gram so that d2_aa == 0 exactly
    if (q == (m >> 2)) {
        int rd = m & 3;
        s_diag[m] = acc[0][0][rd];
        s_diag[16 + m] = acc[1][1][rd];
    }
    __syncthreads();

    // E: dist[a] = sum_b tw[b] * sqrt(d2 masked by d2>0)
#pragma unroll
    for (int ma = 0; ma < 2; ++ma) {
#pragma unroll
        for (int r = 0; r < 4; ++r) {
            int a = ma * 16 + q * 4 + r;
            float da = s_diag[a];
            float g0 = acc[ma][0][r];
            float g1 = acc[ma][1][r];
            int b0 = m;
            int b1 = 16 + m;
            float d20 = da + s_diag[b0] - 2.0f * g0;
            float d21 = da + s_diag[b1] - 2.0f * g1;
            float t0 = (d20 > 0.0f) ? sqrtf(d20) : 0.0f;
            float t1 = (d21 > 0.0f) ? sqrtf(d21) : 0.0f;
            float v = s_tw[b0] * t0 + s_tw[b1] * t1;
            v += __shfl_xor(v, 1);
            v += __shfl_xor(v, 2);
            v += __shfl_xor(v, 4);
            v += __shfl_xor(v, 8);
            if (m == 0) s_dist[a] = v;
        }
    }
    __syncthreads();

    // F: omega = exp(-dist - max(-dist)) * tw, normalized
    {
        int k32 = l & 31;
        float s = s_dist[k32];
        float mn = s;
        mn = fminf(mn, __shfl_xor(mn, 1));
        mn = fminf(mn, __shfl_xor(mn, 2));
        mn = fminf(mn, __shfl_xor(mn, 4));
        mn = fminf(mn, __shfl_xor(mn, 8));
        mn = fminf(mn, __shfl_xor(mn, 16));
        float e = expf(mn - s) * s_tw[k32];
        float sum = e;
        sum += __shfl_xor(sum, 1);
        sum += __shfl_xor(sum, 2);
        sum += __shfl_xor(sum, 4);
        sum += __shfl_xor(sum, 8);
        sum += __shfl_xor(sum, 16);
        float om = e / sum;
        if (l < 32) s_omega[l] = om;
    }
    __syncthreads();

    // G: aggregate from REGISTERS: lane (m,q) contributes omega[m]*row_m +
    // omega[16+m]*row_{16+m} for its element chunks; reduce over m via LDS.
    {
        float w0 = s_omega[m];
        float w1 = s_omega[16 + m];
#pragma unroll
        for (int kt = 0; kt < 4; ++kt) {
            float p[8];
#pragma unroll
            for (int e = 0; e < 8; ++e) {
                float x0 = (float)H0[kt][e] + (float)L0[kt][e];
                float x1 = (float)H1[kt][e] + (float)L1[kt][e];
                p[e] = w0 * x0 + w1 * x1;
            }
            float* dst = &s_red[m * 130 + kt * 32 + q * 8];
            *(float4*)dst = make_float4(p[0], p[1], p[2], p[3]);
            *(float4*)(dst + 4) = make_float4(p[4], p[5], p[6], p[7]);
        }
    }
    __syncthreads();

    {
        int d0 = 2 * l;
        const float2* b2 = (const float2*)bias;
        float2 bb = b2[l];
        float o0 = bb.x;
        float o1 = bb.y;
#pragma unroll
        for (int mm = 0; mm < 16; ++mm) {
            float2 pr = *(const float2*)&s_red[mm * 130 + d0];
            o0 += pr.x;
            o1 += pr.y;
        }
        *(float2*)(outp + (size_t)i * 128 + d0) = make_float2(o0, o1);
    }
}

extern "C" void kernel_launch(void* const* d_in, const int* in_sizes, int n_in,
                              void* d_out, int out_size, void* d_ws, size_t ws_size,
                              hipStream_t stream) {
    const float* feat = (const float*)d_in[0];
    const float* ew = (const float*)d_in[1];
    const float* weight = (const float*)d_in[2];
    const float* bias = (const float*)d_in[3];
    const int* nbr = (const int*)d_in[4];
    float* outp = (float*)d_out;
    int n = in_sizes[0] / NNODE_DIN;  // 50000

    unsigned short* xh = (unsigned short*)d_ws;            // n x 128 bf16
    unsigned short* xl = xh + (size_t)n * NNODE_DOUT;      // n x 128 bf16
    unsigned short* wth = xl + (size_t)n * NNODE_DOUT;     // 2048 frags x 16B
    unsigned short* wtl = wth + 2048 * 8;

    hipLaunchKernelGGL(k0_wprep, dim3(8), dim3(256), 0, stream, weight, wth, wtl);
    int grid1 = (n + 15) / 16;
    hipLaunchKernelGGL(k1_mfma, dim3(grid1), dim3(64), 0, stream, feat, wth, wtl, xh, xl, n);
    hipLaunchKernelGGL(k2_conv, dim3(n), dim3(64), 0, stream, ew, nbr, bias, xh, xl, outp, n);
}